// Round 14
// baseline (382.265 us; speedup 1.0000x reference)
//
#include <hip/hip_runtime.h>
#include <hip/hip_bf16.h>

#define DIN 64
#define DH 128
#define EPSF 1e-5f
#define SLOPE 0.1f

typedef unsigned short u16;
typedef unsigned int u32;
typedef unsigned long long u64;
typedef __attribute__((ext_vector_type(8))) short bf16x8;
typedef __attribute__((ext_vector_type(4))) float f32x4;

#define FIXS 16777216.0f   // 2^24 fixed-point scale for edge weights
#define LDA1 136           // padded LDS row stride (bf16), K=128 tiles
#define LDA0 72            // padded LDS row stride, K=64 tiles

__device__ __forceinline__ float bf2f(u16 u){
    union { u32 i; float f; } v; v.i = ((u32)u) << 16; return v.f;
}
__device__ __forceinline__ u16 f2bf(float f){
    union { float f; u32 i; } v; v.f = f;
    u32 b = v.i;
    b += 0x7FFFu + ((b >> 16) & 1u);    // round to nearest even
    return (u16)(b >> 16);
}
__device__ __forceinline__ u32 pack2(float a, float b){
    return (u32)f2bf(a) | ((u32)f2bf(b) << 16);
}

// ---------------- count: ONE returning u64 atomic per edge, 4 edges/thread ----------------
// At the ~23G atomics/s device ceiling (r9/r10 depth sweeps flat); merging with
// compute kernels LOST ~18us twice (r11/r12) — LDS footprint throttles residency.

__global__ void k_count(const int* __restrict__ dst, const float* __restrict__ ew,
                        u64* packed, int* __restrict__ slotl, int E){
    int base = blockIdx.x * 1024 + threadIdx.x;
    int e0 = base, e1 = base + 256, e2 = base + 512, e3 = base + 768;
    int d0 = 0, d1 = 0, d2 = 0, d3 = 0;
    float w0 = 0, w1 = 0, w2 = 0, w3 = 0;
    bool v0 = e0 < E, v1 = e1 < E, v2 = e2 < E, v3 = e3 < E;
    if (v0){ d0 = dst[e0]; w0 = ew[e0]; }
    if (v1){ d1 = dst[e1]; w1 = ew[e1]; }
    if (v2){ d2 = dst[e2]; w2 = ew[e2]; }
    if (v3){ d3 = dst[e3]; w3 = ew[e3]; }
    u64 o0 = 0, o1 = 0, o2 = 0, o3 = 0;
    if (v0) o0 = atomicAdd(&packed[d0], (1ull << 40) | (u64)(u32)__float2int_rn(w0 * FIXS));
    if (v1) o1 = atomicAdd(&packed[d1], (1ull << 40) | (u64)(u32)__float2int_rn(w1 * FIXS));
    if (v2) o2 = atomicAdd(&packed[d2], (1ull << 40) | (u64)(u32)__float2int_rn(w2 * FIXS));
    if (v3) o3 = atomicAdd(&packed[d3], (1ull << 40) | (u64)(u32)__float2int_rn(w3 * FIXS));
    if (v0) slotl[e0] = (int)(o0 >> 40);
    if (v1) slotl[e1] = (int)(o1 >> 40);
    if (v2) slotl[e2] = (int)(o2 >> 40);
    if (v3) slotl[e3] = (int)(o3 >> 40);
}

// ---------------- GEMM 0 (MFMA bf16): h0 = x@W0, res = x@Wres + bres ----------------

__global__ __launch_bounds__(256) void k_gemm0(const float* __restrict__ x,
        const float* __restrict__ W0, const float* __restrict__ Wres,
        const float* __restrict__ bres, u16* __restrict__ h0,
        u16* __restrict__ res, int N){
    __shared__ u16 xs[64 * LDA0];    // 9 KB
    __shared__ u16 ws[256 * LDA0];   // 36.9 KB
    int tid = threadIdx.x;
    int row0 = blockIdx.x * 64;
    for (int i = tid; i < 256 * 32; i += 256){
        int n = i & 255, k = (i >> 8) * 2;
        int c = n & 127;
        const float* __restrict__ W = (n < 128) ? W0 : Wres;
        float wa = W[k * DH + c], wb = W[(k + 1) * DH + c];
        *(u32*)&ws[n * LDA0 + k] = pack2(wa, wb);
    }
    for (int i = tid; i < 64 * 32; i += 256){
        int r = i >> 5, k2 = (i & 31) * 2;
        int rr = row0 + r; if (rr >= N) rr = N - 1;
        float2 v = *(const float2*)&x[(size_t)rr * DIN + k2];
        *(u32*)&xs[r * LDA0 + k2] = pack2(v.x, v.y);
    }
    __syncthreads();
    int wave = tid >> 6, lane = tid & 63;
    int l15 = lane & 15, kq = (lane >> 4) * 8;
    f32x4 acc[16];
    #pragma unroll
    for (int nt = 0; nt < 16; nt++) acc[nt] = (f32x4){0.f, 0.f, 0.f, 0.f};
    #pragma unroll
    for (int kt = 0; kt < 2; kt++){
        int k0 = kt * 32 + kq;
        bf16x8 a = *(const bf16x8*)&xs[(wave * 16 + l15) * LDA0 + k0];
        #pragma unroll
        for (int nt = 0; nt < 16; nt++){
            bf16x8 b = *(const bf16x8*)&ws[(nt * 16 + l15) * LDA0 + k0];
            acc[nt] = __builtin_amdgcn_mfma_f32_16x16x32_bf16(a, b, acc[nt], 0, 0, 0);
        }
    }
    int rbase = row0 + wave * 16 + (lane >> 4) * 4;
    #pragma unroll
    for (int nt = 0; nt < 16; nt++){
        int col = nt * 16 + l15;
        #pragma unroll
        for (int reg = 0; reg < 4; reg++){
            int rr = rbase + reg;
            if (rr < N){
                if (col < DH) h0[(size_t)rr * DH + col] = f2bf(acc[nt][reg]);
                else          res[(size_t)rr * DH + (col - DH)] = f2bf(acc[nt][reg] + bres[col - DH]);
            }
        }
    }
}

// ---------------- merged scan: per-block local scan + last-block global pass ----------------

__global__ __launch_bounds__(1024) void k_scan(const u64* __restrict__ packed,
        u32* ticket, float* __restrict__ dinv, int* __restrict__ rowstart,
        int* __restrict__ blocksum, float* __restrict__ stats, int N, int E){
    __shared__ int lds[1024];
    __shared__ int flag;
    int t = threadIdx.x;
    int i = blockIdx.x * 1024 + t;
    int v = 0;
    if (i < N){
        u64 p = packed[i];
        float deg = 1.0f + (float)(p & 0xFFFFFFFFFFull) * (1.0f / FIXS);
        dinv[i] = rsqrtf(deg);               // deg >= 1 (self-loop)
        v = (int)(p >> 40);
    }
    lds[t] = v;
    __syncthreads();
    for (int off = 1; off < 1024; off <<= 1){
        int add = (t >= off) ? lds[t - off] : 0;
        __syncthreads();
        lds[t] += add;
        __syncthreads();
    }
    if (i < N) rowstart[i] = lds[t] - v;            // block-local exclusive
    if (t == 1023){
        __hip_atomic_store(&blocksum[blockIdx.x], lds[1023],
                           __ATOMIC_RELEASE, __HIP_MEMORY_SCOPE_AGENT);
        u32 old = __hip_atomic_fetch_add(ticket, 1u,
                           __ATOMIC_ACQ_REL, __HIP_MEMORY_SCOPE_AGENT);
        flag = (old == gridDim.x - 1);
    }
    __syncthreads();
    if (!flag) return;
    // ---- last block only: global phase ----
    if (t < 512) stats[t] = 0.0f;                   // sum0,sq0,sum1,sq1
    if (t < 64){
        int nb = (int)gridDim.x;
        int bv = 0;
        if (t < nb) bv = __hip_atomic_load(&blocksum[t],
                              __ATOMIC_ACQUIRE, __HIP_MEMORY_SCOPE_AGENT);
        int incl = bv;
        #pragma unroll
        for (int off = 1; off < 64; off <<= 1){
            int up = __shfl_up(incl, off, 64);
            if (t >= off) incl += up;
        }
        int excl = incl - bv;
        __hip_atomic_store(&blocksum[t], excl,
                           __ATOMIC_RELEASE, __HIP_MEMORY_SCOPE_AGENT);
        if (t == (N >> 10)) rowstart[N] = E - excl;
    }
}

// ---------------- place edge data, 8 edges/thread; NO atomics ----------------

__global__ void k_place(const int* __restrict__ src, const int* __restrict__ dst,
                        const float* __restrict__ ew, const float* __restrict__ dinv,
                        const int* __restrict__ rowst, const int* __restrict__ blocksum,
                        const int* __restrict__ slotl, u64* __restrict__ edata, int E){
    int base = blockIdx.x * 2048 + threadIdx.x;
    #pragma unroll
    for (int u = 0; u < 8; u++){
        int e = base + u * 256;
        if (e < E){
            int s = src[e], d = dst[e];
            union { float f; u32 i; } c;
            c.f = dinv[s] * ew[e] * dinv[d];
            int slot = rowst[d] + blocksum[d >> 10] + slotl[e];
            edata[slot] = (u64)(u32)s | ((u64)c.i << 32);
        }
    }
}

// ---------------- GEMM 1 (MFMA bf16, fused BN+leaky+residual on input) ----------------

__global__ __launch_bounds__(256) void k_gemm1f(const u16* __restrict__ Bi,
        const u16* __restrict__ Ri, const float* __restrict__ sum,
        const float* __restrict__ sq, const float* __restrict__ g,
        const float* __restrict__ be, const float* __restrict__ W1,
        u16* __restrict__ A, int N, float invN){
    __shared__ u16 xs[64 * LDA1];    // 17.4 KB
    __shared__ u16 ws[128 * LDA1];   // 34.8 KB
    __shared__ float sc[DH], sh[DH];
    int tid = threadIdx.x;
    if (tid < DH){
        float mean = sum[tid] * invN;
        float var  = sq[tid] * invN - mean * mean;
        float s = g[tid] * rsqrtf(var + EPSF);
        sc[tid] = s;
        sh[tid] = be[tid] - mean * s;
    }
    for (int i = tid; i < 128 * 64; i += 256){
        int n = i & 127, k = (i >> 7) * 2;
        float wa = W1[k * DH + n], wb = W1[(k + 1) * DH + n];
        *(u32*)&ws[n * LDA1 + k] = pack2(wa, wb);
    }
    __syncthreads();
    int row0 = blockIdx.x * 64;
    for (int i = tid; i < 64 * 64; i += 256){
        int r = i >> 6, k2 = (i & 63) * 2;
        int rr = row0 + r;
        u32 o = 0;
        if (rr < N){
            u32 bu = *(const u32*)&Bi[(size_t)rr * DH + k2];
            u32 ru = *(const u32*)&Ri[(size_t)rr * DH + k2];
            float t0 = bf2f((u16)bu) * sc[k2] + sh[k2];
            t0 = ((t0 >= 0.f) ? t0 : SLOPE * t0) + bf2f((u16)ru);
            float t1 = bf2f((u16)(bu >> 16)) * sc[k2 + 1] + sh[k2 + 1];
            t1 = ((t1 >= 0.f) ? t1 : SLOPE * t1) + bf2f((u16)(ru >> 16));
            o = pack2(t0, t1);
        }
        *(u32*)&xs[r * LDA1 + k2] = o;
    }
    __syncthreads();
    int wave = tid >> 6, lane = tid & 63;
    int l15 = lane & 15, kq = (lane >> 4) * 8;
    f32x4 acc[8];
    #pragma unroll
    for (int nt = 0; nt < 8; nt++) acc[nt] = (f32x4){0.f, 0.f, 0.f, 0.f};
    #pragma unroll
    for (int kt = 0; kt < 4; kt++){
        int k0 = kt * 32 + kq;
        bf16x8 a = *(const bf16x8*)&xs[(wave * 16 + l15) * LDA1 + k0];
        #pragma unroll
        for (int nt = 0; nt < 8; nt++){
            bf16x8 b = *(const bf16x8*)&ws[(nt * 16 + l15) * LDA1 + k0];
            acc[nt] = __builtin_amdgcn_mfma_f32_16x16x32_bf16(a, b, acc[nt], 0, 0, 0);
        }
    }
    int rbase = row0 + wave * 16 + (lane >> 4) * 4;
    #pragma unroll
    for (int nt = 0; nt < 8; nt++){
        int col = nt * 16 + l15;
        #pragma unroll
        for (int reg = 0; reg < 4; reg++){
            int rr = rbase + reg;
            if (rr < N) A[(size_t)rr * DH + col] = f2bf(acc[nt][reg]);
        }
    }
}

// ---------------- aggregation + BN stats fused: grid-stride, wave per node ----------------
// Each lane owns cols {2l,2l+1} for every node it visits -> BN partials in registers;
// per-block LDS combine + 256 atomicAdds at the end (grid=1024 -> 262k atomics, hidden).

__device__ __forceinline__ void agg_edge(const u16* __restrict__ hin, u64 e,
                                         int col, float& ax, float& ay){
    union { u32 i; float f; } c;
    c.i = (u32)(e >> 32);
    u32 u = *(const u32*)&hin[(size_t)(u32)e * DH + col];
    ax += c.f * bf2f((u16)u);
    ay += c.f * bf2f((u16)(u >> 16));
}

__global__ __launch_bounds__(256) void k_aggbn(const u16* __restrict__ hin,
        u16* __restrict__ out, const float* __restrict__ bias,
        const float* __restrict__ dinv, const int* __restrict__ rowstart,
        const int* __restrict__ blocksum, const u64* __restrict__ edata,
        float* __restrict__ sum, float* __restrict__ sq, int N){
    __shared__ float rs[4][DH], rq[4][DH];
    int tid = threadIdx.x;
    int wave = tid >> 6, lane = tid & 63;
    int col = 2 * lane;
    float bx = bias[col], by = bias[col + 1];
    float s0 = 0.f, s1 = 0.f, q0 = 0.f, q1 = 0.f;
    int ngroups = (N + 3) >> 2;
    for (int grp = blockIdx.x; grp < ngroups; grp += gridDim.x){
        int node = grp * 4 + wave;
        if (node >= N) continue;
        float dn = dinv[node];
        float scf = dn * dn;                  // self-loop coefficient
        u32 hu = *(const u32*)&hin[(size_t)node * DH + col];
        float ax = bx + scf * bf2f((u16)hu);
        float ay = by + scf * bf2f((u16)(hu >> 16));
        int rsn = rowstart[node]     + blocksum[node >> 10];
        int ren = rowstart[node + 1] + blocksum[(node + 1) >> 10];
        int j = rsn;
        for (; j + 7 < ren; j += 8){
            u64 e0 = edata[j],     e1 = edata[j + 1], e2 = edata[j + 2], e3 = edata[j + 3];
            u64 e4 = edata[j + 4], e5 = edata[j + 5], e6 = edata[j + 6], e7 = edata[j + 7];
            agg_edge(hin, e0, col, ax, ay); agg_edge(hin, e1, col, ax, ay);
            agg_edge(hin, e2, col, ax, ay); agg_edge(hin, e3, col, ax, ay);
            agg_edge(hin, e4, col, ax, ay); agg_edge(hin, e5, col, ax, ay);
            agg_edge(hin, e6, col, ax, ay); agg_edge(hin, e7, col, ax, ay);
        }
        if (j + 3 < ren){
            u64 e0 = edata[j], e1 = edata[j + 1], e2 = edata[j + 2], e3 = edata[j + 3];
            agg_edge(hin, e0, col, ax, ay); agg_edge(hin, e1, col, ax, ay);
            agg_edge(hin, e2, col, ax, ay); agg_edge(hin, e3, col, ax, ay);
            j += 4;
        }
        for (; j < ren; j++)
            agg_edge(hin, edata[j], col, ax, ay);
        *(u32*)&out[(size_t)node * DH + col] = pack2(ax, ay);
        s0 += ax; s1 += ay;
        q0 += ax * ax; q1 += ay * ay;
    }
    rs[wave][col] = s0; rs[wave][col + 1] = s1;
    rq[wave][col] = q0; rq[wave][col + 1] = q1;
    __syncthreads();
    if (tid < DH){
        atomicAdd(&sum[tid], rs[0][tid] + rs[1][tid] + rs[2][tid] + rs[3][tid]);
        atomicAdd(&sq[tid],  rq[0][tid] + rq[1][tid] + rq[2][tid] + rq[3][tid]);
    }
}

// ---------------- final: BN apply + leaky + residual + layernorm + store ----------------

__global__ __launch_bounds__(256) void k_lnf(const u16* __restrict__ B,
        const u16* __restrict__ R, const float* __restrict__ sum,
        const float* __restrict__ sq, const float* __restrict__ g,
        const float* __restrict__ be, float* __restrict__ out, int N, float invN){
    int node = blockIdx.x * 4 + (threadIdx.x >> 6);
    int lane = threadIdx.x & 63;
    if (node >= N) return;
    int col = 2 * lane;
    float2 sm  = *(const float2*)&sum[col];
    float2 sqv = *(const float2*)&sq[col];
    float2 gv  = *(const float2*)&g[col];
    float2 bev = *(const float2*)&be[col];
    float m0 = sm.x * invN, m1 = sm.y * invN;
    float va0 = sqv.x * invN - m0 * m0, va1 = sqv.y * invN - m1 * m1;
    float s0 = gv.x * rsqrtf(va0 + EPSF), s1 = gv.y * rsqrtf(va1 + EPSF);
    float h0 = bev.x - m0 * s0, h1 = bev.y - m1 * s1;
    u32 bu = *(const u32*)&B[(size_t)node * DH + col];
    u32 ru = *(const u32*)&R[(size_t)node * DH + col];
    float t0 = bf2f((u16)bu) * s0 + h0;
    t0 = ((t0 >= 0.0f) ? t0 : SLOPE * t0) + bf2f((u16)ru);
    float t1 = bf2f((u16)(bu >> 16)) * s1 + h1;
    t1 = ((t1 >= 0.0f) ? t1 : SLOPE * t1) + bf2f((u16)(ru >> 16));
    float s = t0 + t1;
    float q = t0 * t0 + t1 * t1;
    #pragma unroll
    for (int off = 1; off < 64; off <<= 1){
        s += __shfl_xor(s, off, 64);
        q += __shfl_xor(q, off, 64);
    }
    float mean = s * (1.0f / DH);
    float var  = q * (1.0f / DH) - mean * mean;
    float rstd = rsqrtf(var + EPSF);
    float2 o;
    o.x = (t0 - mean) * rstd;
    o.y = (t1 - mean) * rstd;
    *(float2*)&out[(size_t)node * DH + col] = o;
}

// ---------------- launch ----------------

extern "C" void kernel_launch(void* const* d_in, const int* in_sizes, int n_in,
                              void* d_out, int out_size, void* d_ws, size_t ws_size,
                              hipStream_t stream){
    const float* x    = (const float*)d_in[0];
    const int*   src  = (const int*)d_in[1];
    const int*   dst  = (const int*)d_in[2];
    const float* ew   = (const float*)d_in[3];
    const float* W0   = (const float*)d_in[4];
    const float* b0   = (const float*)d_in[5];
    const float* g0   = (const float*)d_in[6];
    const float* be0  = (const float*)d_in[7];
    const float* W1   = (const float*)d_in[8];
    const float* b1   = (const float*)d_in[9];
    const float* g1   = (const float*)d_in[10];
    const float* be1  = (const float*)d_in[11];
    const float* Wres = (const float*)d_in[12];
    const float* bres = (const float*)d_in[13];
    float* out = (float*)d_out;

    int N = in_sizes[0] / DIN;
    int E = in_sizes[1];
    size_t N128 = (size_t)N * DH;
    float invN = 1.0f / (float)N;

    // workspace layout
    u16* A = (u16*)d_ws;                 // gemm outputs, bf16 [N128]
    u16* B = A + N128;                   // agg outputs, bf16 [N128]
    u16* R = B + N128;                   // residual, bf16 [N128]
    u64* packed = (u64*)(R + N128);      // [N+1]: histogram + ticket word
    u32* ticket = (u32*)&packed[N];
    u64* edata  = packed + N + 1;        // [E] src | coef<<32
    float* dinv = (float*)(edata + E);   // [N]
    int* rowst  = (int*)(dinv + N);      // [N+1] (block-local; +blocksum[i>>10] = global)
    int* slotl  = rowst + N + 1;         // [E]
    float* stats = (float*)(slotl + E);  // 4*DH
    float* sum0 = stats,          *sq0 = stats + DH;
    float* sum1 = stats + 2 * DH, *sq1 = stats + 3 * DH;
    int* blocksum = (int*)(stats + 4 * DH);  // [64]

    int eb4 = (E + 1023) / 1024;
    int eb8 = (E + 2047) / 2048;
    int gb  = (N + 63) / 64;
    int ab4 = (N + 3) / 4;
    int kb  = (N + 1023) / 1024;

    // zero histogram + ticket (DMA node)
    hipMemsetAsync(packed, 0, (size_t)(N + 1) * 8, stream);

    k_count<<<eb4, 256, 0, stream>>>(dst, ew, packed, slotl, E);
    k_gemm0<<<gb, 256, 0, stream>>>(x, W0, Wres, bres, A, R, N);
    k_scan <<<kb, 1024, 0, stream>>>(packed, ticket, dinv, rowst, blocksum, stats, N, E);
    k_place<<<eb8, 256, 0, stream>>>(src, dst, ew, dinv, rowst, blocksum, slotl, edata, E);

    // layer 0: aggregate + BN0 stats in one dispatch
    k_aggbn<<<1024, 256, 0, stream>>>(A, B, b0, dinv, rowst, blocksum, edata, sum0, sq0, N);

    // layer 1 (BN0+leaky+residual fused into gemm1 tile load), then aggregate + BN1 stats
    k_gemm1f<<<gb, 256, 0, stream>>>(B, R, sum0, sq0, g0, be0, W1, A, N, invN);
    k_aggbn <<<1024, 256, 0, stream>>>(A, B, b1, dinv, rowst, blocksum, edata, sum1, sq1, N);

    // BN1+leaky+residual + layernorm fused
    k_lnf   <<<ab4, 256, 0, stream>>>(B, R, sum1, sq1, g1, be1, out, N, invN);
}

// Round 15
// 320.882 us; speedup vs baseline: 1.1913x; 1.1913x over previous
//
#include <hip/hip_runtime.h>
#include <hip/hip_bf16.h>

#define DIN 64
#define DH 128
#define EPSF 1e-5f
#define SLOPE 0.1f
#define NREP 64            // replicated BN-stat buffers (line-spreading for atomics)

typedef unsigned short u16;
typedef unsigned int u32;
typedef unsigned long long u64;
typedef __attribute__((ext_vector_type(8))) short bf16x8;
typedef __attribute__((ext_vector_type(4))) float f32x4;

#define FIXS 16777216.0f   // 2^24 fixed-point scale for edge weights
#define LDA1 136           // padded LDS row stride (bf16), K=128 tiles
#define LDA0 72            // padded LDS row stride, K=64 tiles

__device__ __forceinline__ float bf2f(u16 u){
    union { u32 i; float f; } v; v.i = ((u32)u) << 16; return v.f;
}
__device__ __forceinline__ u16 f2bf(float f){
    union { float f; u32 i; } v; v.f = f;
    u32 b = v.i;
    b += 0x7FFFu + ((b >> 16) & 1u);    // round to nearest even
    return (u16)(b >> 16);
}
__device__ __forceinline__ u32 pack2(float a, float b){
    return (u32)f2bf(a) | ((u32)f2bf(b) << 16);
}

// ---------------- FAT kernel (r11 form, best-measured total): count + gemm0 ----------------
// blocks [0, eb8): one returning u64 atomic per edge, 8 edges/thread.
// blocks [eb8, ...): gemm0 tiles. In-kernel slower than split (LDS caps residency at 3/CU)
// but wins overall by deleting a ~8us graph-node boundary (r11=332.8 vs r13-split=339.3).

__global__ __launch_bounds__(256) void k_cnt_gemm0(
        const int* __restrict__ dst, const float* __restrict__ ew,
        u64* packed, int* __restrict__ slotl, int E, int eb8,
        const float* __restrict__ x, const float* __restrict__ W0,
        const float* __restrict__ Wres, const float* __restrict__ bres,
        u16* __restrict__ h0, u16* __restrict__ res, int N){
    __shared__ u16 xs[64 * LDA0];    // 9 KB
    __shared__ u16 ws[256 * LDA0];   // 36.9 KB
    int tid = threadIdx.x;
    if ((int)blockIdx.x < eb8){
        // ---- count ----
        int base = blockIdx.x * 2048 + tid;
        int  e[8]; bool v[8]; int d[8]; float w[8]; u64 o[8];
        #pragma unroll
        for (int k = 0; k < 8; k++){
            e[k] = base + k * 256;
            v[k] = e[k] < E;
            d[k] = 0; w[k] = 0.0f;
            if (v[k]){ d[k] = dst[e[k]]; w[k] = ew[e[k]]; }
        }
        #pragma unroll
        for (int k = 0; k < 8; k++){
            o[k] = 0;
            if (v[k])
                o[k] = atomicAdd(&packed[d[k]],
                                 (1ull << 40) | (u64)(u32)__float2int_rn(w[k] * FIXS));
        }
        #pragma unroll
        for (int k = 0; k < 8; k++)
            if (v[k]) slotl[e[k]] = (int)(o[k] >> 40);
        return;
    }
    // ---- gemm0: h0 = x@W0, res = x@Wres + bres ----
    int row0 = (blockIdx.x - eb8) * 64;
    for (int i = tid; i < 256 * 32; i += 256){
        int n = i & 255, k = (i >> 8) * 2;
        int c = n & 127;
        const float* __restrict__ W = (n < 128) ? W0 : Wres;
        float wa = W[k * DH + c], wb = W[(k + 1) * DH + c];
        *(u32*)&ws[n * LDA0 + k] = pack2(wa, wb);
    }
    for (int i = tid; i < 64 * 32; i += 256){
        int r = i >> 5, k2 = (i & 31) * 2;
        int rr = row0 + r; if (rr >= N) rr = N - 1;
        float2 v = *(const float2*)&x[(size_t)rr * DIN + k2];
        *(u32*)&xs[r * LDA0 + k2] = pack2(v.x, v.y);
    }
    __syncthreads();
    int wave = tid >> 6, lane = tid & 63;
    int l15 = lane & 15, kq = (lane >> 4) * 8;
    f32x4 acc[16];
    #pragma unroll
    for (int nt = 0; nt < 16; nt++) acc[nt] = (f32x4){0.f, 0.f, 0.f, 0.f};
    #pragma unroll
    for (int kt = 0; kt < 2; kt++){
        int k0 = kt * 32 + kq;
        bf16x8 a = *(const bf16x8*)&xs[(wave * 16 + l15) * LDA0 + k0];
        #pragma unroll
        for (int nt = 0; nt < 16; nt++){
            bf16x8 b = *(const bf16x8*)&ws[(nt * 16 + l15) * LDA0 + k0];
            acc[nt] = __builtin_amdgcn_mfma_f32_16x16x32_bf16(a, b, acc[nt], 0, 0, 0);
        }
    }
    int rbase = row0 + wave * 16 + (lane >> 4) * 4;
    #pragma unroll
    for (int nt = 0; nt < 16; nt++){
        int col = nt * 16 + l15;
        #pragma unroll
        for (int reg = 0; reg < 4; reg++){
            int rr = rbase + reg;
            if (rr < N){
                if (col < DH) h0[(size_t)rr * DH + col] = f2bf(acc[nt][reg]);
                else          res[(size_t)rr * DH + (col - DH)] = f2bf(acc[nt][reg] + bres[col - DH]);
            }
        }
    }
}

// ---------------- merged scan: local scan + last-block global pass; zeroes stat reps ------

__global__ __launch_bounds__(1024) void k_scan(const u64* __restrict__ packed,
        u32* ticket, float* __restrict__ dinv, int* __restrict__ rowstart,
        int* __restrict__ blocksum, float* __restrict__ srep, int N, int E){
    __shared__ int lds[1024];
    __shared__ int flag;
    int t = threadIdx.x;
    int i = blockIdx.x * 1024 + t;
    int v = 0;
    if (i < N){
        u64 p = packed[i];
        float deg = 1.0f + (float)(p & 0xFFFFFFFFFFull) * (1.0f / FIXS);
        dinv[i] = rsqrtf(deg);               // deg >= 1 (self-loop)
        v = (int)(p >> 40);
    }
    lds[t] = v;
    __syncthreads();
    for (int off = 1; off < 1024; off <<= 1){
        int add = (t >= off) ? lds[t - off] : 0;
        __syncthreads();
        lds[t] += add;
        __syncthreads();
    }
    if (i < N) rowstart[i] = lds[t] - v;            // block-local exclusive
    if (t == 1023){
        __hip_atomic_store(&blocksum[blockIdx.x], lds[1023],
                           __ATOMIC_RELEASE, __HIP_MEMORY_SCOPE_AGENT);
        u32 old = __hip_atomic_fetch_add(ticket, 1u,
                           __ATOMIC_ACQ_REL, __HIP_MEMORY_SCOPE_AGENT);
        flag = (old == gridDim.x - 1);
    }
    __syncthreads();
    if (!flag) return;
    // ---- last block only: global phase ----
    for (int z = t; z < 2 * NREP * 256; z += 1024) srep[z] = 0.0f;  // both layers' reps
    if (t < 64){
        int nb = (int)gridDim.x;
        int bv = 0;
        if (t < nb) bv = __hip_atomic_load(&blocksum[t],
                              __ATOMIC_ACQUIRE, __HIP_MEMORY_SCOPE_AGENT);
        int incl = bv;
        #pragma unroll
        for (int off = 1; off < 64; off <<= 1){
            int up = __shfl_up(incl, off, 64);
            if (t >= off) incl += up;
        }
        int excl = incl - bv;
        __hip_atomic_store(&blocksum[t], excl,
                           __ATOMIC_RELEASE, __HIP_MEMORY_SCOPE_AGENT);
        if (t == (N >> 10)) rowstart[N] = E - excl;
    }
}

// ---------------- place edge data, 8 edges/thread; NO atomics ----------------

__global__ void k_place(const int* __restrict__ src, const int* __restrict__ dst,
                        const float* __restrict__ ew, const float* __restrict__ dinv,
                        const int* __restrict__ rowst, const int* __restrict__ blocksum,
                        const int* __restrict__ slotl, u64* __restrict__ edata, int E){
    int base = blockIdx.x * 2048 + threadIdx.x;
    #pragma unroll
    for (int u = 0; u < 8; u++){
        int e = base + u * 256;
        if (e < E){
            int s = src[e], d = dst[e];
            union { float f; u32 i; } c;
            c.f = dinv[s] * ew[e] * dinv[d];
            int slot = rowst[d] + blocksum[d >> 10] + slotl[e];
            edata[slot] = (u64)(u32)s | ((u64)c.i << 32);
        }
    }
}

// ---------------- aggregation + BN stats: grid=2048 (8 blk/CU), wave per node ------------
// Stats flushed to 64 replicated buffers (copy=blockIdx&63) -> 512 same-line atomics/line.

__device__ __forceinline__ void agg_edge(const u16* __restrict__ hin, u64 e,
                                         int col, float& ax, float& ay){
    union { u32 i; float f; } c;
    c.i = (u32)(e >> 32);
    u32 u = *(const u32*)&hin[(size_t)(u32)e * DH + col];
    ax += c.f * bf2f((u16)u);
    ay += c.f * bf2f((u16)(u >> 16));
}

__global__ __launch_bounds__(256) void k_aggbn(const u16* __restrict__ hin,
        u16* __restrict__ out, const float* __restrict__ bias,
        const float* __restrict__ dinv, const int* __restrict__ rowstart,
        const int* __restrict__ blocksum, const u64* __restrict__ edata,
        float* __restrict__ srep, int N){
    __shared__ float rs[4][DH], rq[4][DH];
    int tid = threadIdx.x;
    int wave = tid >> 6, lane = tid & 63;
    int col = 2 * lane;
    float bx = bias[col], by = bias[col + 1];
    float s0 = 0.f, s1 = 0.f, q0 = 0.f, q1 = 0.f;
    int ngroups = (N + 3) >> 2;
    for (int grp = blockIdx.x; grp < ngroups; grp += gridDim.x){
        int node = grp * 4 + wave;
        if (node >= N) continue;
        float dn = dinv[node];
        float scf = dn * dn;                  // self-loop coefficient
        u32 hu = *(const u32*)&hin[(size_t)node * DH + col];
        float ax = bx + scf * bf2f((u16)hu);
        float ay = by + scf * bf2f((u16)(hu >> 16));
        int rsn = rowstart[node]     + blocksum[node >> 10];
        int ren = rowstart[node + 1] + blocksum[(node + 1) >> 10];
        int j = rsn;
        for (; j + 7 < ren; j += 8){
            u64 e0 = edata[j],     e1 = edata[j + 1], e2 = edata[j + 2], e3 = edata[j + 3];
            u64 e4 = edata[j + 4], e5 = edata[j + 5], e6 = edata[j + 6], e7 = edata[j + 7];
            agg_edge(hin, e0, col, ax, ay); agg_edge(hin, e1, col, ax, ay);
            agg_edge(hin, e2, col, ax, ay); agg_edge(hin, e3, col, ax, ay);
            agg_edge(hin, e4, col, ax, ay); agg_edge(hin, e5, col, ax, ay);
            agg_edge(hin, e6, col, ax, ay); agg_edge(hin, e7, col, ax, ay);
        }
        if (j + 3 < ren){
            u64 e0 = edata[j], e1 = edata[j + 1], e2 = edata[j + 2], e3 = edata[j + 3];
            agg_edge(hin, e0, col, ax, ay); agg_edge(hin, e1, col, ax, ay);
            agg_edge(hin, e2, col, ax, ay); agg_edge(hin, e3, col, ax, ay);
            j += 4;
        }
        for (; j < ren; j++)
            agg_edge(hin, edata[j], col, ax, ay);
        *(u32*)&out[(size_t)node * DH + col] = pack2(ax, ay);
        s0 += ax; s1 += ay;
        q0 += ax * ax; q1 += ay * ay;
    }
    rs[wave][col] = s0; rs[wave][col + 1] = s1;
    rq[wave][col] = q0; rq[wave][col + 1] = q1;
    __syncthreads();
    float* rep = srep + (size_t)(blockIdx.x & (NREP - 1)) * 256;
    if (tid < DH)
        atomicAdd(&rep[tid], rs[0][tid] + rs[1][tid] + rs[2][tid] + rs[3][tid]);
    else
        atomicAdd(&rep[tid], rq[0][tid - DH] + rq[1][tid - DH] + rq[2][tid - DH] + rq[3][tid - DH]);
}

// ---------------- GEMM 1 (MFMA bf16, fused BN+leaky+residual; reduces stat reps) ---------

__global__ __launch_bounds__(256) void k_gemm1f(const u16* __restrict__ Bi,
        const u16* __restrict__ Ri, const float* __restrict__ srep,
        const float* __restrict__ g, const float* __restrict__ be,
        const float* __restrict__ W1, u16* __restrict__ A, int N, float invN){
    __shared__ u16 xs[64 * LDA1];    // 17.4 KB
    __shared__ u16 ws[128 * LDA1];   // 34.8 KB
    __shared__ float sc[DH], sh[DH];
    int tid = threadIdx.x;
    if (tid < DH){
        float s = 0.f, q = 0.f;
        #pragma unroll 8
        for (int cp = 0; cp < NREP; cp++){
            s += srep[cp * 256 + tid];
            q += srep[cp * 256 + 128 + tid];
        }
        float mean = s * invN;
        float var  = q * invN - mean * mean;
        float sf = g[tid] * rsqrtf(var + EPSF);
        sc[tid] = sf;
        sh[tid] = be[tid] - mean * sf;
    }
    for (int i = tid; i < 128 * 64; i += 256){
        int n = i & 127, k = (i >> 7) * 2;
        float wa = W1[k * DH + n], wb = W1[(k + 1) * DH + n];
        *(u32*)&ws[n * LDA1 + k] = pack2(wa, wb);
    }
    __syncthreads();
    int row0 = blockIdx.x * 64;
    for (int i = tid; i < 64 * 64; i += 256){
        int r = i >> 6, k2 = (i & 63) * 2;
        int rr = row0 + r;
        u32 o = 0;
        if (rr < N){
            u32 bu = *(const u32*)&Bi[(size_t)rr * DH + k2];
            u32 ru = *(const u32*)&Ri[(size_t)rr * DH + k2];
            float t0 = bf2f((u16)bu) * sc[k2] + sh[k2];
            t0 = ((t0 >= 0.f) ? t0 : SLOPE * t0) + bf2f((u16)ru);
            float t1 = bf2f((u16)(bu >> 16)) * sc[k2 + 1] + sh[k2 + 1];
            t1 = ((t1 >= 0.f) ? t1 : SLOPE * t1) + bf2f((u16)(ru >> 16));
            o = pack2(t0, t1);
        }
        *(u32*)&xs[r * LDA1 + k2] = o;
    }
    __syncthreads();
    int wave = tid >> 6, lane = tid & 63;
    int l15 = lane & 15, kq = (lane >> 4) * 8;
    f32x4 acc[8];
    #pragma unroll
    for (int nt = 0; nt < 8; nt++) acc[nt] = (f32x4){0.f, 0.f, 0.f, 0.f};
    #pragma unroll
    for (int kt = 0; kt < 4; kt++){
        int k0 = kt * 32 + kq;
        bf16x8 a = *(const bf16x8*)&xs[(wave * 16 + l15) * LDA1 + k0];
        #pragma unroll
        for (int nt = 0; nt < 8; nt++){
            bf16x8 b = *(const bf16x8*)&ws[(nt * 16 + l15) * LDA1 + k0];
            acc[nt] = __builtin_amdgcn_mfma_f32_16x16x32_bf16(a, b, acc[nt], 0, 0, 0);
        }
    }
    int rbase = row0 + wave * 16 + (lane >> 4) * 4;
    #pragma unroll
    for (int nt = 0; nt < 8; nt++){
        int col = nt * 16 + l15;
        #pragma unroll
        for (int reg = 0; reg < 4; reg++){
            int rr = rbase + reg;
            if (rr < N) A[(size_t)rr * DH + col] = f2bf(acc[nt][reg]);
        }
    }
}

// ---------------- final: BN apply + leaky + residual + layernorm (reduces stat reps) -----

__global__ __launch_bounds__(256) void k_lnf(const u16* __restrict__ B,
        const u16* __restrict__ R, const float* __restrict__ srep,
        const float* __restrict__ g, const float* __restrict__ be,
        float* __restrict__ out, int N, float invN){
    __shared__ float sc[DH], sh[DH];
    int tid = threadIdx.x;
    if (tid < DH){
        float s = 0.f, q = 0.f;
        #pragma unroll 8
        for (int cp = 0; cp < NREP; cp++){
            s += srep[cp * 256 + tid];
            q += srep[cp * 256 + 128 + tid];
        }
        float mean = s * invN;
        float var  = q * invN - mean * mean;
        float sf = g[tid] * rsqrtf(var + EPSF);
        sc[tid] = sf;
        sh[tid] = be[tid] - mean * sf;
    }
    __syncthreads();
    int node = blockIdx.x * 4 + (tid >> 6);
    int lane = tid & 63;
    if (node >= N) return;
    int col = 2 * lane;
    u32 bu = *(const u32*)&B[(size_t)node * DH + col];
    u32 ru = *(const u32*)&R[(size_t)node * DH + col];
    float t0 = bf2f((u16)bu) * sc[col] + sh[col];
    t0 = ((t0 >= 0.0f) ? t0 : SLOPE * t0) + bf2f((u16)ru);
    float t1 = bf2f((u16)(bu >> 16)) * sc[col + 1] + sh[col + 1];
    t1 = ((t1 >= 0.0f) ? t1 : SLOPE * t1) + bf2f((u16)(ru >> 16));
    float s = t0 + t1;
    float q = t0 * t0 + t1 * t1;
    #pragma unroll
    for (int off = 1; off < 64; off <<= 1){
        s += __shfl_xor(s, off, 64);
        q += __shfl_xor(q, off, 64);
    }
    float mean = s * (1.0f / DH);
    float var  = q * (1.0f / DH) - mean * mean;
    float rstd = rsqrtf(var + EPSF);
    float2 o;
    o.x = (t0 - mean) * rstd;
    o.y = (t1 - mean) * rstd;
    *(float2*)&out[(size_t)node * DH + col] = o;
}

// ---------------- launch ----------------

extern "C" void kernel_launch(void* const* d_in, const int* in_sizes, int n_in,
                              void* d_out, int out_size, void* d_ws, size_t ws_size,
                              hipStream_t stream){
    const float* x    = (const float*)d_in[0];
    const int*   src  = (const int*)d_in[1];
    const int*   dst  = (const int*)d_in[2];
    const float* ew   = (const float*)d_in[3];
    const float* W0   = (const float*)d_in[4];
    const float* b0   = (const float*)d_in[5];
    const float* g0   = (const float*)d_in[6];
    const float* be0  = (const float*)d_in[7];
    const float* W1   = (const float*)d_in[8];
    const float* b1   = (const float*)d_in[9];
    const float* g1   = (const float*)d_in[10];
    const float* be1  = (const float*)d_in[11];
    const float* Wres = (const float*)d_in[12];
    const float* bres = (const float*)d_in[13];
    float* out = (float*)d_out;

    int N = in_sizes[0] / DIN;
    int E = in_sizes[1];
    size_t N128 = (size_t)N * DH;
    float invN = 1.0f / (float)N;

    // workspace layout
    u16* A = (u16*)d_ws;                 // gemm outputs, bf16 [N128]
    u16* B = A + N128;                   // agg outputs, bf16 [N128]
    u16* R = B + N128;                   // residual, bf16 [N128]
    u64* packed = (u64*)(R + N128);      // [N+1]: histogram + ticket word
    u32* ticket = (u32*)&packed[N];
    u64* edata  = packed + N + 1;        // [E] src | coef<<32
    float* dinv = (float*)(edata + E);   // [N]
    int* rowst  = (int*)(dinv + N);      // [N+1] (block-local; +blocksum[i>>10] = global)
    int* slotl  = rowst + N + 1;         // [E]
    float* srep0 = (float*)(slotl + E);  // [NREP*256] layer-0 sum|sq reps
    float* srep1 = srep0 + NREP * 256;   // [NREP*256] layer-1
    int* blocksum = (int*)(srep1 + NREP * 256);  // [64]

    int eb8 = (E + 2047) / 2048;
    int gb  = (N + 63) / 64;
    int ab4 = (N + 3) / 4;
    int kb  = (N + 1023) / 1024;

    // zero histogram + ticket (DMA node); stat reps zeroed inside k_scan
    hipMemsetAsync(packed, 0, (size_t)(N + 1) * 8, stream);

    k_cnt_gemm0<<<eb8 + gb, 256, 0, stream>>>(dst, ew, packed, slotl, E, eb8,
                                              x, W0, Wres, bres, A, R, N);
    k_scan <<<kb, 1024, 0, stream>>>(packed, ticket, dinv, rowst, blocksum, srep0, N, E);
    k_place<<<eb8, 256, 0, stream>>>(src, dst, ew, dinv, rowst, blocksum, slotl, edata, E);

    // layer 0: aggregate + BN0 stats (replicated)
    k_aggbn<<<2048, 256, 0, stream>>>(A, B, b0, dinv, rowst, blocksum, edata, srep0, N);

    // layer 1: BN0+leaky+residual fused into gemm1 tile load (reduces srep0)
    k_gemm1f<<<gb, 256, 0, stream>>>(B, R, srep0, g0, be0, W1, A, N, invN);
    k_aggbn <<<2048, 256, 0, stream>>>(A, B, b1, dinv, rowst, blocksum, edata, srep1, N);

    // BN1+leaky+residual + layernorm fused (reduces srep1)
    k_lnf   <<<ab4, 256, 0, stream>>>(B, R, srep1, g1, be1, out, N, invN);
}

// Round 16
// 310.319 us; speedup vs baseline: 1.2318x; 1.0340x over previous
//
#include <hip/hip_runtime.h>
#include <hip/hip_bf16.h>

#define DIN 64
#define DH 128
#define EPSF 1e-5f
#define SLOPE 0.1f
#define NREP 64            // replicated BN-stat buffers (line-spreading for atomics)

typedef unsigned short u16;
typedef unsigned int u32;
typedef unsigned long long u64;
typedef __attribute__((ext_vector_type(8))) short bf16x8;
typedef __attribute__((ext_vector_type(4))) float f32x4;

#define FIXS 16777216.0f   // 2^24 fixed-point scale for edge weights
#define LDA1 136           // padded LDS row stride (bf16), K=128 tiles
#define LDA0 72            // padded LDS row stride, K=64 tiles

__device__ __forceinline__ float bf2f(u16 u){
    union { u32 i; float f; } v; v.i = ((u32)u) << 16; return v.f;
}
__device__ __forceinline__ u16 f2bf(float f){
    union { float f; u32 i; } v; v.f = f;
    u32 b = v.i;
    b += 0x7FFFu + ((b >> 16) & 1u);    // round to nearest even
    return (u16)(b >> 16);
}
__device__ __forceinline__ u32 pack2(float a, float b){
    return (u32)f2bf(a) | ((u32)f2bf(b) << 16);
}

// ---------------- FAT kernel: count + gemm0 (64x64 tiles, 18.4 KB LDS) ----------------
// r11/r15 form had 45.9 KB LDS -> 3 blocks/CU -> count blocks starved (68.9us, occ 17.8%).
// 64-col tiles cut LDS to 18.4 KB -> ~8 blocks/CU so count's atomic-latency blocks and
// gemm's MFMA blocks co-reside properly. Count: 1 returning u64 atomic/edge, 8/thread.

__global__ __launch_bounds__(256) void k_cnt_gemm0(
        const int* __restrict__ dst, const float* __restrict__ ew,
        u64* packed, int* __restrict__ slotl, int E, int eb8, int gb,
        const float* __restrict__ x, const float* __restrict__ W0,
        const float* __restrict__ Wres, const float* __restrict__ bres,
        u16* __restrict__ h0, u16* __restrict__ res, int N){
    __shared__ u16 xs[64 * LDA0];    // 9.2 KB
    __shared__ u16 ws[64 * LDA0];    // 9.2 KB (64 out-cols x K=64)
    int tid = threadIdx.x;
    if ((int)blockIdx.x < eb8){
        // ---- count ----
        int base = blockIdx.x * 2048 + tid;
        int  e[8]; bool v[8]; int d[8]; float w[8]; u64 o[8];
        #pragma unroll
        for (int k = 0; k < 8; k++){
            e[k] = base + k * 256;
            v[k] = e[k] < E;
            d[k] = 0; w[k] = 0.0f;
            if (v[k]){ d[k] = dst[e[k]]; w[k] = ew[e[k]]; }
        }
        #pragma unroll
        for (int k = 0; k < 8; k++){
            o[k] = 0;
            if (v[k])
                o[k] = atomicAdd(&packed[d[k]],
                                 (1ull << 40) | (u64)(u32)__float2int_rn(w[k] * FIXS));
        }
        #pragma unroll
        for (int k = 0; k < 8; k++)
            if (v[k]) slotl[e[k]] = (int)(o[k] >> 40);
        return;
    }
    // ---- gemm0 tile: 64 rows x 64 cols of (h0 | res) ----
    int gid = blockIdx.x - eb8;
    int cg = gid / gb;                 // 0:W0[0:64) 1:W0[64:128) 2:Wres[0:64) 3:Wres[64:128)
    int row0 = (gid - cg * gb) * 64;
    const float* __restrict__ W = (cg < 2) ? W0 : Wres;
    int cb = (cg & 1) * 64;            // global col base within the 128-col matrix
    for (int i = tid; i < 64 * 32; i += 256){
        int n = i & 63, k = (i >> 6) * 2;
        float wa = W[k * DH + cb + n], wb = W[(k + 1) * DH + cb + n];
        *(u32*)&ws[n * LDA0 + k] = pack2(wa, wb);
    }
    for (int i = tid; i < 64 * 32; i += 256){
        int r = i >> 5, k2 = (i & 31) * 2;
        int rr = row0 + r; if (rr >= N) rr = N - 1;
        float2 v = *(const float2*)&x[(size_t)rr * DIN + k2];
        *(u32*)&xs[r * LDA0 + k2] = pack2(v.x, v.y);
    }
    __syncthreads();
    int wave = tid >> 6, lane = tid & 63;
    int l15 = lane & 15, kq = (lane >> 4) * 8;
    f32x4 acc[4];
    #pragma unroll
    for (int nt = 0; nt < 4; nt++) acc[nt] = (f32x4){0.f, 0.f, 0.f, 0.f};
    #pragma unroll
    for (int kt = 0; kt < 2; kt++){
        int k0 = kt * 32 + kq;
        bf16x8 a = *(const bf16x8*)&xs[(wave * 16 + l15) * LDA0 + k0];
        #pragma unroll
        for (int nt = 0; nt < 4; nt++){
            bf16x8 b = *(const bf16x8*)&ws[(nt * 16 + l15) * LDA0 + k0];
            acc[nt] = __builtin_amdgcn_mfma_f32_16x16x32_bf16(a, b, acc[nt], 0, 0, 0);
        }
    }
    int rbase = row0 + wave * 16 + (lane >> 4) * 4;
    #pragma unroll
    for (int nt = 0; nt < 4; nt++){
        int col = cb + nt * 16 + l15;
        #pragma unroll
        for (int reg = 0; reg < 4; reg++){
            int rr = rbase + reg;
            if (rr < N){
                if (cg < 2) h0[(size_t)rr * DH + col] = f2bf(acc[nt][reg]);
                else        res[(size_t)rr * DH + col] = f2bf(acc[nt][reg] + bres[col]);
            }
        }
    }
}

// ---------------- merged scan: local scan + last-block global pass; zeroes stat reps ------

__global__ __launch_bounds__(1024) void k_scan(const u64* __restrict__ packed,
        u32* ticket, float* __restrict__ dinv, int* __restrict__ rowstart,
        int* __restrict__ blocksum, float* __restrict__ srep, int N, int E){
    __shared__ int lds[1024];
    __shared__ int flag;
    int t = threadIdx.x;
    int i = blockIdx.x * 1024 + t;
    int v = 0;
    if (i < N){
        u64 p = packed[i];
        float deg = 1.0f + (float)(p & 0xFFFFFFFFFFull) * (1.0f / FIXS);
        dinv[i] = rsqrtf(deg);               // deg >= 1 (self-loop)
        v = (int)(p >> 40);
    }
    lds[t] = v;
    __syncthreads();
    for (int off = 1; off < 1024; off <<= 1){
        int add = (t >= off) ? lds[t - off] : 0;
        __syncthreads();
        lds[t] += add;
        __syncthreads();
    }
    if (i < N) rowstart[i] = lds[t] - v;            // block-local exclusive
    if (t == 1023){
        __hip_atomic_store(&blocksum[blockIdx.x], lds[1023],
                           __ATOMIC_RELEASE, __HIP_MEMORY_SCOPE_AGENT);
        u32 old = __hip_atomic_fetch_add(ticket, 1u,
                           __ATOMIC_ACQ_REL, __HIP_MEMORY_SCOPE_AGENT);
        flag = (old == gridDim.x - 1);
    }
    __syncthreads();
    if (!flag) return;
    // ---- last block only: global phase ----
    for (int z = t; z < 2 * NREP * 256; z += 1024) srep[z] = 0.0f;  // both layers' reps
    if (t < 64){
        int nb = (int)gridDim.x;
        int bv = 0;
        if (t < nb) bv = __hip_atomic_load(&blocksum[t],
                              __ATOMIC_ACQUIRE, __HIP_MEMORY_SCOPE_AGENT);
        int incl = bv;
        #pragma unroll
        for (int off = 1; off < 64; off <<= 1){
            int up = __shfl_up(incl, off, 64);
            if (t >= off) incl += up;
        }
        int excl = incl - bv;
        __hip_atomic_store(&blocksum[t], excl,
                           __ATOMIC_RELEASE, __HIP_MEMORY_SCOPE_AGENT);
        if (t == (N >> 10)) rowstart[N] = E - excl;
    }
}

// ---------------- place edge data, 8 edges/thread; NO atomics ----------------

__global__ void k_place(const int* __restrict__ src, const int* __restrict__ dst,
                        const float* __restrict__ ew, const float* __restrict__ dinv,
                        const int* __restrict__ rowst, const int* __restrict__ blocksum,
                        const int* __restrict__ slotl, u64* __restrict__ edata, int E){
    int base = blockIdx.x * 2048 + threadIdx.x;
    #pragma unroll
    for (int u = 0; u < 8; u++){
        int e = base + u * 256;
        if (e < E){
            int s = src[e], d = dst[e];
            union { float f; u32 i; } c;
            c.f = dinv[s] * ew[e] * dinv[d];
            int slot = rowst[d] + blocksum[d >> 10] + slotl[e];
            edata[slot] = (u64)(u32)s | ((u64)c.i << 32);
        }
    }
}

// ---------------- aggregation + BN stats: grid=2048 (8 blk/CU), wave per node ------------
// Stats flushed to 64 replicated buffers (copy=blockIdx&63) -> 512 same-line atomics/line.

__device__ __forceinline__ void agg_edge(const u16* __restrict__ hin, u64 e,
                                         int col, float& ax, float& ay){
    union { u32 i; float f; } c;
    c.i = (u32)(e >> 32);
    u32 u = *(const u32*)&hin[(size_t)(u32)e * DH + col];
    ax += c.f * bf2f((u16)u);
    ay += c.f * bf2f((u16)(u >> 16));
}

__global__ __launch_bounds__(256) void k_aggbn(const u16* __restrict__ hin,
        u16* __restrict__ out, const float* __restrict__ bias,
        const float* __restrict__ dinv, const int* __restrict__ rowstart,
        const int* __restrict__ blocksum, const u64* __restrict__ edata,
        float* __restrict__ srep, int N){
    __shared__ float rs[4][DH], rq[4][DH];
    int tid = threadIdx.x;
    int wave = tid >> 6, lane = tid & 63;
    int col = 2 * lane;
    float bx = bias[col], by = bias[col + 1];
    float s0 = 0.f, s1 = 0.f, q0 = 0.f, q1 = 0.f;
    int ngroups = (N + 3) >> 2;
    for (int grp = blockIdx.x; grp < ngroups; grp += gridDim.x){
        int node = grp * 4 + wave;
        if (node >= N) continue;
        float dn = dinv[node];
        float scf = dn * dn;                  // self-loop coefficient
        u32 hu = *(const u32*)&hin[(size_t)node * DH + col];
        float ax = bx + scf * bf2f((u16)hu);
        float ay = by + scf * bf2f((u16)(hu >> 16));
        int rsn = rowstart[node]     + blocksum[node >> 10];
        int ren = rowstart[node + 1] + blocksum[(node + 1) >> 10];
        int j = rsn;
        for (; j + 7 < ren; j += 8){
            u64 e0 = edata[j],     e1 = edata[j + 1], e2 = edata[j + 2], e3 = edata[j + 3];
            u64 e4 = edata[j + 4], e5 = edata[j + 5], e6 = edata[j + 6], e7 = edata[j + 7];
            agg_edge(hin, e0, col, ax, ay); agg_edge(hin, e1, col, ax, ay);
            agg_edge(hin, e2, col, ax, ay); agg_edge(hin, e3, col, ax, ay);
            agg_edge(hin, e4, col, ax, ay); agg_edge(hin, e5, col, ax, ay);
            agg_edge(hin, e6, col, ax, ay); agg_edge(hin, e7, col, ax, ay);
        }
        if (j + 3 < ren){
            u64 e0 = edata[j], e1 = edata[j + 1], e2 = edata[j + 2], e3 = edata[j + 3];
            agg_edge(hin, e0, col, ax, ay); agg_edge(hin, e1, col, ax, ay);
            agg_edge(hin, e2, col, ax, ay); agg_edge(hin, e3, col, ax, ay);
            j += 4;
        }
        for (; j < ren; j++)
            agg_edge(hin, edata[j], col, ax, ay);
        *(u32*)&out[(size_t)node * DH + col] = pack2(ax, ay);
        s0 += ax; s1 += ay;
        q0 += ax * ax; q1 += ay * ay;
    }
    rs[wave][col] = s0; rs[wave][col + 1] = s1;
    rq[wave][col] = q0; rq[wave][col + 1] = q1;
    __syncthreads();
    float* rep = srep + (size_t)(blockIdx.x & (NREP - 1)) * 256;
    if (tid < DH)
        atomicAdd(&rep[tid], rs[0][tid] + rs[1][tid] + rs[2][tid] + rs[3][tid]);
    else
        atomicAdd(&rep[tid], rq[0][tid - DH] + rq[1][tid - DH] + rq[2][tid - DH] + rq[3][tid - DH]);
}

// ---------------- GEMM 1 (MFMA bf16, fused BN+leaky+residual; reduces stat reps) ---------

__global__ __launch_bounds__(256) void k_gemm1f(const u16* __restrict__ Bi,
        const u16* __restrict__ Ri, const float* __restrict__ srep,
        const float* __restrict__ g, const float* __restrict__ be,
        const float* __restrict__ W1, u16* __restrict__ A, int N, float invN){
    __shared__ u16 xs[64 * LDA1];    // 17.4 KB
    __shared__ u16 ws[128 * LDA1];   // 34.8 KB
    __shared__ float sc[DH], sh[DH];
    int tid = threadIdx.x;
    if (tid < DH){
        float s = 0.f, q = 0.f;
        #pragma unroll 8
        for (int cp = 0; cp < NREP; cp++){
            s += srep[cp * 256 + tid];
            q += srep[cp * 256 + 128 + tid];
        }
        float mean = s * invN;
        float var  = q * invN - mean * mean;
        float sf = g[tid] * rsqrtf(var + EPSF);
        sc[tid] = sf;
        sh[tid] = be[tid] - mean * sf;
    }
    for (int i = tid; i < 128 * 64; i += 256){
        int n = i & 127, k = (i >> 7) * 2;
        float wa = W1[k * DH + n], wb = W1[(k + 1) * DH + n];
        *(u32*)&ws[n * LDA1 + k] = pack2(wa, wb);
    }
    __syncthreads();
    int row0 = blockIdx.x * 64;
    for (int i = tid; i < 64 * 64; i += 256){
        int r = i >> 6, k2 = (i & 63) * 2;
        int rr = row0 + r;
        u32 o = 0;
        if (rr < N){
            u32 bu = *(const u32*)&Bi[(size_t)rr * DH + k2];
            u32 ru = *(const u32*)&Ri[(size_t)rr * DH + k2];
            float t0 = bf2f((u16)bu) * sc[k2] + sh[k2];
            t0 = ((t0 >= 0.f) ? t0 : SLOPE * t0) + bf2f((u16)ru);
            float t1 = bf2f((u16)(bu >> 16)) * sc[k2 + 1] + sh[k2 + 1];
            t1 = ((t1 >= 0.f) ? t1 : SLOPE * t1) + bf2f((u16)(ru >> 16));
            o = pack2(t0, t1);
        }
        *(u32*)&xs[r * LDA1 + k2] = o;
    }
    __syncthreads();
    int wave = tid >> 6, lane = tid & 63;
    int l15 = lane & 15, kq = (lane >> 4) * 8;
    f32x4 acc[8];
    #pragma unroll
    for (int nt = 0; nt < 8; nt++) acc[nt] = (f32x4){0.f, 0.f, 0.f, 0.f};
    #pragma unroll
    for (int kt = 0; kt < 4; kt++){
        int k0 = kt * 32 + kq;
        bf16x8 a = *(const bf16x8*)&xs[(wave * 16 + l15) * LDA1 + k0];
        #pragma unroll
        for (int nt = 0; nt < 8; nt++){
            bf16x8 b = *(const bf16x8*)&ws[(nt * 16 + l15) * LDA1 + k0];
            acc[nt] = __builtin_amdgcn_mfma_f32_16x16x32_bf16(a, b, acc[nt], 0, 0, 0);
        }
    }
    int rbase = row0 + wave * 16 + (lane >> 4) * 4;
    #pragma unroll
    for (int nt = 0; nt < 8; nt++){
        int col = nt * 16 + l15;
        #pragma unroll
        for (int reg = 0; reg < 4; reg++){
            int rr = rbase + reg;
            if (rr < N) A[(size_t)rr * DH + col] = f2bf(acc[nt][reg]);
        }
    }
}

// ---------------- final: BN apply + leaky + residual + layernorm (reduces stat reps) -----

__global__ __launch_bounds__(256) void k_lnf(const u16* __restrict__ B,
        const u16* __restrict__ R, const float* __restrict__ srep,
        const float* __restrict__ g, const float* __restrict__ be,
        float* __restrict__ out, int N, float invN){
    __shared__ float sc[DH], sh[DH];
    int tid = threadIdx.x;
    if (tid < DH){
        float s = 0.f, q = 0.f;
        #pragma unroll 8
        for (int cp = 0; cp < NREP; cp++){
            s += srep[cp * 256 + tid];
            q += srep[cp * 256 + 128 + tid];
        }
        float mean = s * invN;
        float var  = q * invN - mean * mean;
        float sf = g[tid] * rsqrtf(var + EPSF);
        sc[tid] = sf;
        sh[tid] = be[tid] - mean * sf;
    }
    __syncthreads();
    int node = blockIdx.x * 4 + (tid >> 6);
    int lane = tid & 63;
    if (node >= N) return;
    int col = 2 * lane;
    u32 bu = *(const u32*)&B[(size_t)node * DH + col];
    u32 ru = *(const u32*)&R[(size_t)node * DH + col];
    float t0 = bf2f((u16)bu) * sc[col] + sh[col];
    t0 = ((t0 >= 0.0f) ? t0 : SLOPE * t0) + bf2f((u16)ru);
    float t1 = bf2f((u16)(bu >> 16)) * sc[col + 1] + sh[col + 1];
    t1 = ((t1 >= 0.0f) ? t1 : SLOPE * t1) + bf2f((u16)(ru >> 16));
    float s = t0 + t1;
    float q = t0 * t0 + t1 * t1;
    #pragma unroll
    for (int off = 1; off < 64; off <<= 1){
        s += __shfl_xor(s, off, 64);
        q += __shfl_xor(q, off, 64);
    }
    float mean = s * (1.0f / DH);
    float var  = q * (1.0f / DH) - mean * mean;
    float rstd = rsqrtf(var + EPSF);
    float2 o;
    o.x = (t0 - mean) * rstd;
    o.y = (t1 - mean) * rstd;
    *(float2*)&out[(size_t)node * DH + col] = o;
}

// ---------------- launch ----------------

extern "C" void kernel_launch(void* const* d_in, const int* in_sizes, int n_in,
                              void* d_out, int out_size, void* d_ws, size_t ws_size,
                              hipStream_t stream){
    const float* x    = (const float*)d_in[0];
    const int*   src  = (const int*)d_in[1];
    const int*   dst  = (const int*)d_in[2];
    const float* ew   = (const float*)d_in[3];
    const float* W0   = (const float*)d_in[4];
    const float* b0   = (const float*)d_in[5];
    const float* g0   = (const float*)d_in[6];
    const float* be0  = (const float*)d_in[7];
    const float* W1   = (const float*)d_in[8];
    const float* b1   = (const float*)d_in[9];
    const float* g1   = (const float*)d_in[10];
    const float* be1  = (const float*)d_in[11];
    const float* Wres = (const float*)d_in[12];
    const float* bres = (const float*)d_in[13];
    float* out = (float*)d_out;

    int N = in_sizes[0] / DIN;
    int E = in_sizes[1];
    size_t N128 = (size_t)N * DH;
    float invN = 1.0f / (float)N;

    // workspace layout
    u16* A = (u16*)d_ws;                 // gemm outputs, bf16 [N128]
    u16* B = A + N128;                   // agg outputs, bf16 [N128]
    u16* R = B + N128;                   // residual, bf16 [N128]
    u64* packed = (u64*)(R + N128);      // [N+1]: histogram + ticket word
    u32* ticket = (u32*)&packed[N];
    u64* edata  = packed + N + 1;        // [E] src | coef<<32
    float* dinv = (float*)(edata + E);   // [N]
    int* rowst  = (int*)(dinv + N);      // [N+1] (block-local; +blocksum[i>>10] = global)
    int* slotl  = rowst + N + 1;         // [E]
    float* srep0 = (float*)(slotl + E);  // [NREP*256] layer-0 sum|sq reps
    float* srep1 = srep0 + NREP * 256;   // [NREP*256] layer-1
    int* blocksum = (int*)(srep1 + NREP * 256);  // [64]

    int eb8 = (E + 2047) / 2048;
    int gb  = (N + 63) / 64;
    int ab4 = (N + 3) / 4;
    int kb  = (N + 1023) / 1024;

    // zero histogram + ticket (DMA node); stat reps zeroed inside k_scan
    hipMemsetAsync(packed, 0, (size_t)(N + 1) * 8, stream);

    k_cnt_gemm0<<<eb8 + 4 * gb, 256, 0, stream>>>(dst, ew, packed, slotl, E, eb8, gb,
                                                  x, W0, Wres, bres, A, R, N);
    k_scan <<<kb, 1024, 0, stream>>>(packed, ticket, dinv, rowst, blocksum, srep0, N, E);
    k_place<<<eb8, 256, 0, stream>>>(src, dst, ew, dinv, rowst, blocksum, slotl, edata, E);

    // layer 0: aggregate + BN0 stats (replicated)
    k_aggbn<<<2048, 256, 0, stream>>>(A, B, b0, dinv, rowst, blocksum, edata, srep0, N);

    // layer 1: BN0+leaky+residual fused into gemm1 tile load (reduces srep0)
    k_gemm1f<<<gb, 256, 0, stream>>>(B, R, srep0, g0, be0, W1, A, N, invN);
    k_aggbn <<<2048, 256, 0, stream>>>(A, B, b1, dinv, rowst, blocksum, edata, srep1, N);

    // BN1+leaky+residual + layernorm fused (reduces srep1)
    k_lnf   <<<ab4, 256, 0, stream>>>(B, R, srep1, g1, be1, out, N, invN);
}